// Round 1
// baseline (14646.465 us; speedup 1.0000x reference)
//
#include <hip/hip_runtime.h>

#define BB 16
#define NN 4096
#define SS 1024
#define KK 32
#define MPTS (BB*SS*KK)      // 524288
#define EPSF 1e-5f

// workspace layout (float offsets)
#define OFF_Q     0                       // B*S*3 = 49152
#define OFF_X2    (OFF_Q + BB*SS*3)       // B*N   = 65536
#define OFF_ST    (OFF_X2 + BB*NN)        // stats block (512 floats, zeroed each call)
#define OFF_MOM   (OFF_ST)                // 27 used
#define OFF_S1SUM (OFF_ST+32)             // 64
#define OFF_S1SQ  (OFF_ST+96)             // 64
#define OFF_S2SUM (OFF_ST+160)            // 128
#define OFF_S2SQ  (OFF_ST+288)            // 128
#define OFF_SC0   (OFF_ST+512)
#define OFF_SH0   (OFF_SC0+64)
#define OFF_SC1   (OFF_SH0+64)
#define OFF_SH1   (OFF_SC1+64)
#define OFF_XG    (OFF_SH1+64)            // 6*MPTS = 3145728 (channel-major)
#define OFF_MAXB  (OFF_XG + 6*MPTS)       // B*S*128
#define OFF_MINB  (OFF_MAXB + BB*SS*128)  // B*S*128  -> total ~29.8 MB

__global__ __launch_bounds__(256) void prep_kernel(
    const float* __restrict__ xyz, const int* __restrict__ fps,
    float* __restrict__ out, float* __restrict__ ws)
{
  const int g = blockIdx.x*256 + threadIdx.x;
  if (g < BB*NN){
    const float* p = xyz + (size_t)g*3;
    float x=p[0], y=p[1], z=p[2];
    ws[OFF_X2+g] = __fadd_rn(__fadd_rn(__fmul_rn(x,x),__fmul_rn(y,y)),__fmul_rn(z,z));
  } else {
    int j = g - BB*NN;
    if (j < BB*SS){
      int b = j >> 10;
      int idx = fps[j];
      const float* p = xyz + ((size_t)b*NN + idx)*3;
      float x=p[0], y=p[1], z=p[2];
      out[(size_t)j*3+0]=x; out[(size_t)j*3+1]=y; out[(size_t)j*3+2]=z;
      ws[OFF_Q+(size_t)j*3+0]=x; ws[OFF_Q+(size_t)j*3+1]=y; ws[OFF_Q+(size_t)j*3+2]=z;
    }
  }
}

// one block per query: exact 32-NN via radix-select on orderable float bits,
// writes grouped input (channel-major) and accumulates layer-0 input moments.
__global__ __launch_bounds__(256) void knn_group_kernel(
    const float* __restrict__ xyz, const float* __restrict__ pts,
    float* __restrict__ ws)
{
  __shared__ unsigned keys[NN];
  __shared__ unsigned hist[256];
  __shared__ unsigned sh_bin, sh_knew;
  __shared__ int sh_nlt, sh_neq;
  __shared__ int sel[KK];
  __shared__ int eqlist[256];

  const int bid = blockIdx.x;
  const int b = bid >> 10;
  const int tid = threadIdx.x;

  const float* qp = ws + OFF_Q + (size_t)bid*3;
  const float qx = qp[0], qy = qp[1], qz = qp[2];
  const float q2 = __fadd_rn(__fadd_rn(__fmul_rn(qx,qx),__fmul_rn(qy,qy)),__fmul_rn(qz,qz));
  const float* xb  = xyz + (size_t)b*NN*3;
  const float* x2b = ws + OFF_X2 + (size_t)b*NN;

  #pragma unroll
  for (int j=0;j<16;j++){
    int n = tid + j*256;
    float X = xb[n*3+0], Y = xb[n*3+1], Z = xb[n*3+2];
    float dot = __fadd_rn(__fadd_rn(__fmul_rn(qx,X),__fmul_rn(qy,Y)),__fmul_rn(qz,Z));
    float d = __fsub_rn(__fadd_rn(q2, x2b[n]), __fmul_rn(2.0f,dot));
    unsigned u = __float_as_uint(d);
    keys[n] = u ^ (unsigned)(((int)u>>31) | (int)0x80000000);
  }
  __syncthreads();

  unsigned prefix = 0;
  int kk = KK;
  for (int pass=3; pass>=0; --pass){
    const int shift = pass*8;
    const unsigned maskhi = (pass==3) ? 0u : (0xFFFFFFFFu << (shift+8));
    hist[tid] = 0;
    __syncthreads();
    #pragma unroll
    for (int j=0;j<16;j++){
      unsigned key = keys[tid + j*256];
      if ((key & maskhi) == prefix) atomicAdd(&hist[(key>>shift)&0xFFu], 1u);
    }
    __syncthreads();
    for (int off=1; off<256; off<<=1){
      unsigned v = hist[tid];
      if (tid >= off) v += hist[tid-off];
      __syncthreads();
      hist[tid] = v;
      __syncthreads();
    }
    unsigned cumt  = hist[tid];
    unsigned lower = (tid==0)?0u:hist[tid-1];
    if (cumt >= (unsigned)kk && lower < (unsigned)kk){
      sh_bin = (unsigned)tid; sh_knew = (unsigned)kk - lower;
    }
    __syncthreads();
    prefix |= (sh_bin << shift);
    kk = (int)sh_knew;
    __syncthreads();
  }
  const unsigned v32 = prefix;

  if (tid==0){ sh_nlt = 0; sh_neq = 0; }
  __syncthreads();
  #pragma unroll
  for (int j=0;j<16;j++){
    int n = tid + j*256;
    unsigned key = keys[n];
    if (key < v32){ int p = atomicAdd(&sh_nlt,1); sel[p] = n; }
    else if (key == v32){ int p = atomicAdd(&sh_neq,1); if (p < 256) eqlist[p] = n; }
  }
  __syncthreads();
  if (tid==0){
    int nlt = sh_nlt;
    int need = KK - nlt;
    int neq = sh_neq;
    if (neq <= 256){
      for (int a=0;a<need;a++){          // lowest-index ties first (top_k semantics)
        int mi = a;
        for (int c=a+1;c<neq;c++) if (eqlist[c] < eqlist[mi]) mi = c;
        int t = eqlist[a]; eqlist[a]=eqlist[mi]; eqlist[mi]=t;
        sel[nlt+a] = eqlist[a];
      }
    } else {
      int got = 0;
      for (int n=0;n<NN && got<need;n++) if (keys[n]==v32){ sel[nlt+got]=n; ++got; }
    }
  }
  __syncthreads();

  if (tid < KK){
    int n = sel[tid];
    const float* pp = xb + (size_t)n*3;
    float v[6];
    v[0] = pp[0]-qx; v[1] = pp[1]-qy; v[2] = pp[2]-qz;
    const float* pt = pts + ((size_t)b*NN + n)*3;
    v[3] = pt[0]; v[4] = pt[1]; v[5] = pt[2];
    size_t pidx = (size_t)bid*KK + tid;
    float* xg = ws + OFF_XG;
    #pragma unroll
    for (int c=0;c<6;c++) xg[(size_t)c*MPTS + pidx] = v[c];
    // layer-0 input moments (6 sums + 21 upper-tri products)
    float m[27];
    int mi = 0;
    #pragma unroll
    for (int c=0;c<6;c++) m[mi++] = v[c];
    #pragma unroll
    for (int c=0;c<6;c++){
      #pragma unroll
      for (int c2=c;c2<6;c2++) m[mi++] = v[c]*v[c2];
    }
    #pragma unroll
    for (int off=16; off>=1; off>>=1){
      #pragma unroll
      for (int q=0;q<27;q++) m[q] += __shfl_xor(m[q], off, 64);
    }
    if (tid==0){
      float* mom = ws + OFF_MOM;
      #pragma unroll
      for (int q=0;q<27;q++) atomicAdd(&mom[q], m[q]);
    }
  }
}

__global__ void finalize0_kernel(const float* __restrict__ w0, const float* __restrict__ b0,
                                 const float* __restrict__ g0, const float* __restrict__ t0,
                                 float* __restrict__ ws)
{
  int o = threadIdx.x; // 64 threads
  const float* mom = ws + OFF_MOM;
  float w[6];
  #pragma unroll
  for (int c=0;c<6;c++) w[c] = w0[o*6+c];
  float bo = b0[o];
  float wS = 0.f;
  #pragma unroll
  for (int c=0;c<6;c++) wS += w[c]*mom[c];
  const float Mf = (float)MPTS;
  float mean = (wS + Mf*bo) / Mf;
  float qsum = 0.f;
  int mi = 6;
  #pragma unroll
  for (int c=0;c<6;c++){
    #pragma unroll
    for (int c2=c;c2<6;c2++){
      float f = (c==c2)?1.f:2.f;
      qsum += f * w[c]*w[c2]*mom[mi];
      mi++;
    }
  }
  float E2  = (qsum + 2.f*bo*wS + Mf*bo*bo) / Mf;
  float var = E2 - mean*mean;
  float sc  = g0[o] / sqrtf(var + EPSF);
  ws[OFF_SC0+o] = sc;
  ws[OFF_SH0+o] = t0[o] - mean*sc;
}

// recompute y0 -> h0 -> y1raw, accumulate layer-1 stats (no stores)
__global__ __launch_bounds__(256) void layer1_stats_kernel(
    const float* __restrict__ w0g, const float* __restrict__ b0g,
    const float* __restrict__ w1g, const float* __restrict__ b1g,
    float* __restrict__ ws)
{
  __shared__ __align__(16) float sw0[384];
  __shared__ float sb0[64], ssc0[64], ssh0[64];
  __shared__ __align__(16) float sw1[4096];
  __shared__ float sb1[64];
  __shared__ float red[128];
  const int tid = threadIdx.x;
  for (int i=tid;i<384;i+=256)  sw0[i]=w0g[i];
  for (int i=tid;i<4096;i+=256) sw1[i]=w1g[i];
  if (tid<64){ sb0[tid]=b0g[tid]; sb1[tid]=b1g[tid];
               ssc0[tid]=ws[OFF_SC0+tid]; ssh0[tid]=ws[OFF_SH0+tid]; }
  if (tid<128) red[tid]=0.f;
  __syncthreads();

  const size_t p = (size_t)blockIdx.x*256 + tid;
  const float* xg = ws + OFF_XG;
  float x[6];
  #pragma unroll
  for (int c=0;c<6;c++) x[c] = xg[(size_t)c*MPTS + p];

  float acc[64];
  #pragma unroll
  for (int o=0;o<64;o++) acc[o] = sb1[o];

  for (int c0=0;c0<64;c0+=4){
    float h[4];
    #pragma unroll
    for (int j=0;j<4;j++){
      int o = c0+j;
      float y = sb0[o];
      #pragma unroll
      for (int c=0;c<6;c++) y = fmaf(sw0[o*6+c], x[c], y);
      h[j] = fmaxf(fmaf(ssc0[o], y, ssh0[o]), 0.f);
    }
    #pragma unroll
    for (int o=0;o<64;o++){
      const float4 wv = *reinterpret_cast<const float4*>(&sw1[o*64+c0]);
      acc[o] = fmaf(wv.x, h[0], acc[o]);
      acc[o] = fmaf(wv.y, h[1], acc[o]);
      acc[o] = fmaf(wv.z, h[2], acc[o]);
      acc[o] = fmaf(wv.w, h[3], acc[o]);
    }
  }
  const int lane = tid & 63;
  #pragma unroll
  for (int o=0;o<64;o++){
    float sv = acc[o];
    float sq = acc[o]*acc[o];
    #pragma unroll
    for (int off=32; off>=1; off>>=1){
      sv += __shfl_xor(sv, off, 64);
      sq += __shfl_xor(sq, off, 64);
    }
    if (lane == o){
      atomicAdd(&red[o],    sv);
      atomicAdd(&red[64+o], sq);
    }
  }
  __syncthreads();
  if (tid < 128) atomicAdd(&ws[OFF_S1SUM + tid], red[tid]);
}

__global__ void finalize1_kernel(const float* __restrict__ g1, const float* __restrict__ t1,
                                 float* __restrict__ ws)
{
  int o = threadIdx.x;
  const float Mf = (float)MPTS;
  float mean = ws[OFF_S1SUM+o]/Mf;
  float var  = ws[OFF_S1SQ+o]/Mf - mean*mean;
  float sc = g1[o]/sqrtf(var+EPSF);
  ws[OFF_SC1+o]=sc; ws[OFF_SH1+o]=t1[o]-mean*sc;
}

// recompute full chain, accumulate layer-2 stats + per-group raw max/min of y2
__global__ __launch_bounds__(256) void layer2_max_kernel(
    const float* __restrict__ w0g, const float* __restrict__ b0g,
    const float* __restrict__ w1g, const float* __restrict__ b1g,
    const float* __restrict__ w2g, const float* __restrict__ b2g,
    float* __restrict__ ws)
{
  __shared__ __align__(16) float sw0[384];
  __shared__ float sb0[64], ssc0[64], ssh0[64];
  __shared__ __align__(16) float sw1[4096];
  __shared__ float sb1[64], ssc1[64], ssh1[64];
  __shared__ __align__(16) float sw2[8192];
  __shared__ float sb2[128];
  __shared__ float red[256];
  const int tid = threadIdx.x;
  for (int i=tid;i<384;i+=256)  sw0[i]=w0g[i];
  for (int i=tid;i<4096;i+=256) sw1[i]=w1g[i];
  for (int i=tid;i<8192;i+=256) sw2[i]=w2g[i];
  if (tid<64){ sb0[tid]=b0g[tid]; sb1[tid]=b1g[tid];
               ssc0[tid]=ws[OFF_SC0+tid]; ssh0[tid]=ws[OFF_SH0+tid];
               ssc1[tid]=ws[OFF_SC1+tid]; ssh1[tid]=ws[OFF_SH1+tid]; }
  if (tid<128) sb2[tid]=b2g[tid];
  red[tid]=0.f;
  __syncthreads();

  const size_t p = (size_t)blockIdx.x*256 + tid;
  const float* xg = ws + OFF_XG;
  float x[6];
  #pragma unroll
  for (int c=0;c<6;c++) x[c] = xg[(size_t)c*MPTS + p];

  // h1 = relu(bn1(W1 h0 + b1)), h0 = relu(bn0(W0 x + b0))
  float h1[64];
  #pragma unroll
  for (int o=0;o<64;o++) h1[o] = sb1[o];
  for (int c0=0;c0<64;c0+=4){
    float h[4];
    #pragma unroll
    for (int j=0;j<4;j++){
      int o = c0+j;
      float y = sb0[o];
      #pragma unroll
      for (int c=0;c<6;c++) y = fmaf(sw0[o*6+c], x[c], y);
      h[j] = fmaxf(fmaf(ssc0[o], y, ssh0[o]), 0.f);
    }
    #pragma unroll
    for (int o=0;o<64;o++){
      const float4 wv = *reinterpret_cast<const float4*>(&sw1[o*64+c0]);
      h1[o] = fmaf(wv.x,h[0],h1[o]); h1[o] = fmaf(wv.y,h[1],h1[o]);
      h1[o] = fmaf(wv.z,h[2],h1[o]); h1[o] = fmaf(wv.w,h[3],h1[o]);
    }
  }
  #pragma unroll
  for (int o=0;o<64;o++) h1[o] = fmaxf(fmaf(ssc1[o], h1[o], ssh1[o]), 0.f);

  const int lane = tid & 63;
  const int l32  = tid & 31;
  const size_t gidx = p >> 5;
  float* maxb = ws + OFF_MAXB;
  float* minb = ws + OFF_MINB;

  // two halves of the 128 outputs to bound register pressure
  for (int half=0; half<2; ++half){
    const int obase = half*64;
    float acc[64];
    #pragma unroll
    for (int o=0;o<64;o++) acc[o] = sb2[obase+o];
    #pragma unroll
    for (int c0=0;c0<64;c0+=4){
      #pragma unroll
      for (int o=0;o<64;o++){
        const float4 wv = *reinterpret_cast<const float4*>(&sw2[(obase+o)*64+c0]);
        acc[o] = fmaf(wv.x,h1[c0+0],acc[o]); acc[o] = fmaf(wv.y,h1[c0+1],acc[o]);
        acc[o] = fmaf(wv.z,h1[c0+2],acc[o]); acc[o] = fmaf(wv.w,h1[c0+3],acc[o]);
      }
    }
    #pragma unroll
    for (int o=0;o<64;o++){
      float sv = acc[o], sq = acc[o]*acc[o];
      #pragma unroll
      for (int off=32; off>=1; off>>=1){
        sv += __shfl_xor(sv,off,64);
        sq += __shfl_xor(sq,off,64);
      }
      if (lane == o){
        atomicAdd(&red[obase+o],     sv);
        atomicAdd(&red[128+obase+o], sq);
      }
      float mx = acc[o], mn = acc[o];
      #pragma unroll
      for (int off=16; off>=1; off>>=1){
        mx = fmaxf(mx, __shfl_xor(mx,off,64));
        mn = fminf(mn, __shfl_xor(mn,off,64));
      }
      if (l32 == (o & 31)){
        maxb[gidx*128 + obase + o] = mx;
        minb[gidx*128 + obase + o] = mn;
      }
    }
  }
  __syncthreads();
  atomicAdd(&ws[OFF_S2SUM + tid], red[tid]);
}

__global__ __launch_bounds__(256) void final_out_kernel(
    const float* __restrict__ g2, const float* __restrict__ t2,
    const float* __restrict__ ws, float* __restrict__ out)
{
  const int g = blockIdx.x*256 + threadIdx.x; // B*S*128 threads
  const int o = g & 127;
  const float Mf = (float)MPTS;
  float mean = ws[OFF_S2SUM+o] / Mf;
  float var  = ws[OFF_S2SQ+o] / Mf - mean*mean;
  float sc = g2[o] / sqrtf(var + EPSF);
  float sh = t2[o] - mean*sc;
  // relu(sc*y+sh) is monotone in y: use group max if sc>0 else group min
  float v = (sc > 0.f) ? ws[OFF_MAXB+g] : ws[OFF_MINB+g];
  out[BB*SS*3 + g] = fmaxf(fmaf(sc, v, sh), 0.f);
}

extern "C" void kernel_launch(void* const* d_in, const int* in_sizes, int n_in,
                              void* d_out, int out_size, void* d_ws, size_t ws_size,
                              hipStream_t stream)
{
  const float* xyz = (const float*)d_in[0];
  const float* pts = (const float*)d_in[1];
  const int*   fps = (const int*)d_in[2];
  const float* w0  = (const float*)d_in[3];
  const float* b0  = (const float*)d_in[4];
  const float* g0  = (const float*)d_in[5];
  const float* t0  = (const float*)d_in[6];
  const float* w1  = (const float*)d_in[7];
  const float* b1  = (const float*)d_in[8];
  const float* g1  = (const float*)d_in[9];
  const float* t1  = (const float*)d_in[10];
  const float* w2  = (const float*)d_in[11];
  const float* b2  = (const float*)d_in[12];
  const float* g2  = (const float*)d_in[13];
  const float* t2  = (const float*)d_in[14];
  float* out = (float*)d_out;
  float* ws  = (float*)d_ws;

  hipMemsetAsync((void*)(ws + OFF_ST), 0, 512*sizeof(float), stream);
  prep_kernel<<<320,256,0,stream>>>(xyz, fps, out, ws);
  knn_group_kernel<<<BB*SS,256,0,stream>>>(xyz, pts, ws);
  finalize0_kernel<<<1,64,0,stream>>>(w0,b0,g0,t0,ws);
  layer1_stats_kernel<<<MPTS/256,256,0,stream>>>(w0,b0,w1,b1,ws);
  finalize1_kernel<<<1,64,0,stream>>>(g1,t1,ws);
  layer2_max_kernel<<<MPTS/256,256,0,stream>>>(w0,b0,w1,b1,w2,b2,ws);
  final_out_kernel<<<(BB*SS*128)/256,256,0,stream>>>(g2,t2,ws,out);
}